// Round 3
// baseline (19353.392 us; speedup 1.0000x reference)
//
#include <hip/hip_runtime.h>
#include <math.h>

// 4-layer tanh RNN (H=2048, T=512) + FC on last timestep.
// Round-3 design:
//  - Persistent kernel, 256 blocks x 512 threads (1 block/CU, proven resident).
//  - DEPTH-4 layer pipeline: layer = blk>>6, 64 blocks/layer, all 4 layers run
//    concurrently with ~1-step lag. Critical path ~T+3 handshakes (vs 2T).
//  - Column-sliced waves: wave w owns cols [w*256,(w+1)*256); its sentinel
//    poll loads ARE the operand fetch (16B/lane own-h + 16B/lane prev-h),
//    feeding FMAs directly from registers. No LDS exchange, no barrier-1.
//  - 32 rows/block: Whh fp32 in VGPRs (128), W_ih bf16-RNE packed (64 regs).
//  - Distributed halving shuffle-reduce (xor32 pre-level + 5 halving levels);
//    lane<32 ends holding row bitrev5(lane); partial[t&1][8][32] in LDS,
//    ONE barrier/step, wave 0 finalizes (sum 8 + bias + fast tanh) and
//    publishes 32 rows with a single 128B agent store.
//  - Handshake = data-as-flag: buffers prefilled 0xFFFFFFFF (NaN, tanh can
//    never produce it); slot 0 zeroed = h_{-1}. Agent-scope 8B atomic loads.
//  - FC done by the layer-3 group (w_fc loaded after Whh is dead).

#define HH 2048
#define TT 512
#define NBLK 256
#define LBLK 64       // blocks per layer
#define ROWS 32       // rows per block
#define NTH 512

typedef unsigned long long u64;
typedef unsigned int u32;

__device__ __forceinline__ u64 ld_a8(const float* p) {
  return __hip_atomic_load((const u64*)p, __ATOMIC_RELAXED,
                           __HIP_MEMORY_SCOPE_AGENT);
}
__device__ __forceinline__ void st_a4(float* p, float v) {
  __hip_atomic_store(p, v, __ATOMIC_RELAXED, __HIP_MEMORY_SCOPE_AGENT);
}
__device__ __forceinline__ bool fresh8(u64 v) {
  return ((u32)v != 0xFFFFFFFFu) & ((u32)(v >> 32) != 0xFFFFFFFFu);
}
__device__ __forceinline__ u32 bf16rne(float f) {
  u32 x = __float_as_uint(f);
  return (x + 0x7fffu + ((x >> 16) & 1u)) >> 16;
}
__device__ __forceinline__ float bflo(u32 p) { return __uint_as_float(p << 16); }
__device__ __forceinline__ float bfhi(u32 p) { return __uint_as_float(p & 0xffff0000u); }
__device__ __forceinline__ float fast_tanh(float s) {
  float e = __expf(2.f * s);          // inf for large s -> 1; 0 for -large -> -1
  return 1.f - 2.f / (e + 1.f);
}

__launch_bounds__(NTH, 2)
__global__ void rnn_d4(const float* __restrict__ x,
                       const float* __restrict__ w_ih,
                       const float* __restrict__ w_hh,
                       const float* __restrict__ b_ih,
                       const float* __restrict__ b_hh,
                       const float* __restrict__ w_fc,
                       const float* __restrict__ b_fc,
                       float* __restrict__ out,
                       float* ws)
{
  const int blk  = blockIdx.x;
  const int l    = blk >> 6;          // layer 0..3
  const int gb   = blk & (LBLK - 1);  // block within layer
  const int tid  = threadIdx.x;
  const int wid  = tid >> 6;
  const int lane = tid & 63;
  const int scol = wid * 256 + lane * 4;   // this lane's 4 columns

  float* outB      = ws + (size_t)l * (TT + 1) * HH;
  const float* inB = ws + (size_t)(l - 1) * (TT + 1) * HH;  // l>0 only

  __shared__ float partial[2][8][32];

  // ---- weights into VGPRs (once): Whh fp32 [32][4], Wih bf16x2 [32][2] ----
  float whh[ROWS][4];
  u32   wihp[ROWS][2];
#pragma unroll
  for (int r = 0; r < ROWS; ++r) {
    const size_t rowoff = ((size_t)l * HH + gb * ROWS + r) * HH + scol;
    const float4 vh = *(const float4*)(w_hh + rowoff);
    whh[r][0] = vh.x; whh[r][1] = vh.y; whh[r][2] = vh.z; whh[r][3] = vh.w;
    const float4 vi = *(const float4*)(w_ih + rowoff);
    wihp[r][0] = bf16rne(vi.x) | (bf16rne(vi.y) << 16);
    wihp[r][1] = bf16rne(vi.z) | (bf16rne(vi.w) << 16);
  }
  float fbias = 0.f;
  if (wid == 0 && lane < 32)
    fbias = b_ih[l * HH + gb * ROWS + lane] + b_hh[l * HH + gb * ROWS + lane];

  // row this lane will own after the distributed reduce: bitrev5(lane&31)
  const int rrow = ((lane & 1) << 4) | ((lane & 2) << 2) | (lane & 4) |
                   ((lane & 8) >> 2) | ((lane & 16) >> 4);

  const float* po = outB + scol;            // own slot t (starts at t=0)
  const float* pp = inB + HH + scol;        // prev slot t+1
  float* ps = outB + HH + gb * ROWS + lane; // wave0 store ptr (slot t+1)
  const float* xb = x + (size_t)scol * TT;  // x[scol][t]

  for (int t = 0; t < TT; ++t) {
    // hoisted x gather (layer 0 only) — independent of the poll
    float xg0 = 0.f, xg1 = 0.f, xg2 = 0.f, xg3 = 0.f;
    if (l == 0) {
      xg0 = xb[0 * TT + t]; xg1 = xb[1 * TT + t];
      xg2 = xb[2 * TT + t]; xg3 = xb[3 * TT + t];
    }

    // ---- sentinel poll: own h_{t-1} slice (+ prev-layer h_t slice) ----
    u64 o0, o1, p0 = 0, p1 = 0;
    for (;;) {
      o0 = ld_a8(po);
      o1 = ld_a8(po + 2);
      if (l > 0) { p0 = ld_a8(pp); p1 = ld_a8(pp + 2); }
      bool ok = fresh8(o0) & fresh8(o1);
      if (l > 0) ok = ok & fresh8(p0) & fresh8(p1);
      if (__all(ok)) break;
      __builtin_amdgcn_s_sleep(1);
    }
    float hh0 = __uint_as_float((u32)o0), hh1 = __uint_as_float((u32)(o0 >> 32));
    float hh2 = __uint_as_float((u32)o1), hh3 = __uint_as_float((u32)(o1 >> 32));
    float hi0, hi1, hi2, hi3;
    if (l == 0) { hi0 = xg0; hi1 = xg1; hi2 = xg2; hi3 = xg3; }
    else {
      hi0 = __uint_as_float((u32)p0); hi1 = __uint_as_float((u32)(p0 >> 32));
      hi2 = __uint_as_float((u32)p1); hi3 = __uint_as_float((u32)(p1 >> 32));
    }

    // ---- per-lane partial matvec: 32 rows x 4 cols (both matrices) ----
    float acc[ROWS];
#pragma unroll
    for (int r = 0; r < ROWS; ++r) {
      float a = whh[r][0] * hh0 + whh[r][1] * hh1 +
                whh[r][2] * hh2 + whh[r][3] * hh3;
      a += bflo(wihp[r][0]) * hi0 + bfhi(wihp[r][0]) * hi1;
      a += bflo(wihp[r][1]) * hi2 + bfhi(wihp[r][1]) * hi3;
      acc[r] = a;
    }

    // ---- distributed reduce: xor-32 pre-level, then 5 halving levels ----
#pragma unroll
    for (int i = 0; i < 32; ++i) acc[i] += __shfl_xor(acc[i], 32, 64);
#pragma unroll
    for (int lv = 0; lv < 5; ++lv) {
      const int m = 1 << lv;
      const int n = 16 >> lv;          // 16,8,4,2,1
      const bool up = (lane & m) != 0;
#pragma unroll
      for (int i = 0; i < 16; ++i) {
        if (i < n) {
          float mine   = up ? acc[i + n] : acc[i];
          float theirs = __shfl_xor(up ? acc[i] : acc[i + n], m, 64);
          acc[i] = mine + theirs;
        }
      }
    }
    if (lane < 32) partial[t & 1][wid][rrow] = acc[0];
    __syncthreads();                    // the ONLY barrier per step

    if (wid == 0 && lane < 32) {
      float s = fbias;
#pragma unroll
      for (int w = 0; w < 8; ++w) s += partial[t & 1][w][lane];
      st_a4(ps, fast_tanh(s));
    }
    po += HH; pp += HH; ps += HH;
    // partial[] race-freedom: wave w's step-(t+1) write targets buffer
    // (t+1)&1, which wave 0 finished reading at step t-1; any wave's step
    // t+2 (same buffer as t) is gated through other blocks' step t+1, which
    // needs OUR slot t+1, which wave 0 stores only after its step-t reads.
  }

  // ---- FC on h3[T-1]: layer-3 group only (Whh regs are dead now) ----
  if (l == 3) {
    float wf[ROWS][4];
#pragma unroll
    for (int r = 0; r < ROWS; ++r) {
      const float4 v = *(const float4*)(w_fc + (size_t)(gb * ROWS + r) * HH + scol);
      wf[r][0] = v.x; wf[r][1] = v.y; wf[r][2] = v.z; wf[r][3] = v.w;
    }
    const float* ph = outB + (size_t)TT * HH + scol;
    u64 o0, o1;
    for (;;) {
      o0 = ld_a8(ph);
      o1 = ld_a8(ph + 2);
      if (__all(fresh8(o0) & fresh8(o1))) break;
      __builtin_amdgcn_s_sleep(1);
    }
    float h0 = __uint_as_float((u32)o0), h1 = __uint_as_float((u32)(o0 >> 32));
    float h2 = __uint_as_float((u32)o1), h3 = __uint_as_float((u32)(o1 >> 32));

    float acc[ROWS];
#pragma unroll
    for (int r = 0; r < ROWS; ++r)
      acc[r] = wf[r][0] * h0 + wf[r][1] * h1 + wf[r][2] * h2 + wf[r][3] * h3;
#pragma unroll
    for (int i = 0; i < 32; ++i) acc[i] += __shfl_xor(acc[i], 32, 64);
#pragma unroll
    for (int lv = 0; lv < 5; ++lv) {
      const int m = 1 << lv;
      const int n = 16 >> lv;
      const bool up = (lane & m) != 0;
#pragma unroll
      for (int i = 0; i < 16; ++i) {
        if (i < n) {
          float mine   = up ? acc[i + n] : acc[i];
          float theirs = __shfl_xor(up ? acc[i] : acc[i + n], m, 64);
          acc[i] = mine + theirs;
        }
      }
    }
    if (lane < 32) partial[0][wid][rrow] = acc[0];
    __syncthreads();
    if (wid == 0 && lane < 32) {
      float s = b_fc[gb * ROWS + lane];
#pragma unroll
      for (int w = 0; w < 8; ++w) s += partial[0][w][lane];
      out[gb * ROWS + lane] = s;
    }
  }
}

extern "C" void kernel_launch(void* const* d_in, const int* in_sizes, int n_in,
                              void* d_out, int out_size, void* d_ws, size_t ws_size,
                              hipStream_t stream) {
  const float* x    = (const float*)d_in[0];
  const float* w_ih = (const float*)d_in[1];
  const float* w_hh = (const float*)d_in[2];
  const float* b_ih = (const float*)d_in[3];
  const float* b_hh = (const float*)d_in[4];
  const float* w_fc = (const float*)d_in[5];
  const float* b_fc = (const float*)d_in[6];
  float* out = (float*)d_out;
  float* ws  = (float*)d_ws;

  // 4 exchange buffers (one per layer): (TT+1) x HH floats each.
  // Sentinel-fill, then zero slot 0 (= h_{-1}) of each.
  const size_t bufFloats = (size_t)(TT + 1) * HH;
  hipMemsetAsync(ws, 0xFF, 4 * bufFloats * sizeof(float), stream);
  for (int l = 0; l < 4; ++l)
    hipMemsetAsync(ws + l * bufFloats, 0, HH * sizeof(float), stream);

  rnn_d4<<<NBLK, NTH, 0, stream>>>(x, w_ih, w_hh, b_ih, b_hh,
                                   w_fc, b_fc, out, ws);
}

// Round 4
// 8861.227 us; speedup vs baseline: 2.1841x; 2.1841x over previous
//
#include <hip/hip_runtime.h>
#include <math.h>

// 4-layer tanh RNN (H=2048, T=512) + FC on last timestep.
// Round-4: round-3 depth-4 structure with the REGISTER SPILL FIXED.
//  - Root cause of r3 regression: whh fp32[32][4]+wih bf16 = ~250 reg demand
//    > 256 unified VGPR+AGPR cap -> scratch spill -> 28 GB HBM fetch.
//  - Fix: BOTH weight matrices stored f16-packed (half2), consumed via
//    v_dot2_f32_f16 (fp32 accumulator, 2 MAC/instr). Weight regs: 128 u32.
//    Total demand ~200 < 256. Also 4x fewer VALU ops in the hot loop.
//  - Everything else as round 3: 256 blocks x 512 thr (1/CU), layer=blk>>6,
//    64 blocks/layer, 32 rows/block, column-sliced waves polling their own
//    16B/lane slice (data-as-flag sentinel 0xFFFFFFFF), poll regs feed dot
//    products directly, distributed halving reduce, ONE barrier/step,
//    wave 0 finalizes (fp32 bias + tanh) and publishes 32 rows.

#define HH 2048
#define TT 512
#define NBLK 256
#define LBLK 64       // blocks per layer
#define ROWS 32       // rows per block
#define NTH 512

typedef unsigned long long u64;
typedef unsigned int u32;
typedef _Float16 h2 __attribute__((ext_vector_type(2)));

#if defined(__has_builtin)
#if __has_builtin(__builtin_amdgcn_fdot2)
#define HAS_FDOT2 1
#endif
#endif

__device__ __forceinline__ u64 ld_a8(const float* p) {
  return __hip_atomic_load((const u64*)p, __ATOMIC_RELAXED,
                           __HIP_MEMORY_SCOPE_AGENT);
}
__device__ __forceinline__ void st_a4(float* p, float v) {
  __hip_atomic_store(p, v, __ATOMIC_RELAXED, __HIP_MEMORY_SCOPE_AGENT);
}
__device__ __forceinline__ bool fresh8(u64 v) {
  return ((u32)v != 0xFFFFFFFFu) & ((u32)(v >> 32) != 0xFFFFFFFFu);
}
__device__ __forceinline__ h2 pk2(float a, float b) {
  h2 r; r[0] = (_Float16)a; r[1] = (_Float16)b; return r;   // RNE converts
}
__device__ __forceinline__ float dot2(h2 a, h2 b, float c) {
#ifdef HAS_FDOT2
  return __builtin_amdgcn_fdot2(a, b, c, false);
#else
  return c + (float)a[0] * (float)b[0] + (float)a[1] * (float)b[1];
#endif
}
__device__ __forceinline__ float fast_tanh(float s) {
  float e = __expf(2.f * s);          // inf for large s -> 1; 0 -> -1
  return 1.f - 2.f / (e + 1.f);
}

__launch_bounds__(NTH, 2)
__global__ void rnn_d4(const float* __restrict__ x,
                       const float* __restrict__ w_ih,
                       const float* __restrict__ w_hh,
                       const float* __restrict__ b_ih,
                       const float* __restrict__ b_hh,
                       const float* __restrict__ w_fc,
                       const float* __restrict__ b_fc,
                       float* __restrict__ out,
                       float* ws)
{
  const int blk  = blockIdx.x;
  const int l    = blk >> 6;          // layer 0..3
  const int gb   = blk & (LBLK - 1);  // block within layer
  const int tid  = threadIdx.x;
  const int wid  = tid >> 6;
  const int lane = tid & 63;
  const int scol = wid * 256 + lane * 4;   // this lane's 4 columns

  float* outB      = ws + (size_t)l * (TT + 1) * HH;
  const float* inB = ws + (size_t)(l - 1) * (TT + 1) * HH;  // l>0 only

  __shared__ float partial[2][8][32];

  // ---- weights into VGPRs (once), f16-packed: [32][2] half2 each ----
  h2 whh[ROWS][2], wih[ROWS][2];
#pragma unroll
  for (int r = 0; r < ROWS; ++r) {
    const size_t rowoff = ((size_t)l * HH + gb * ROWS + r) * HH + scol;
    const float4 vh = *(const float4*)(w_hh + rowoff);
    whh[r][0] = pk2(vh.x, vh.y); whh[r][1] = pk2(vh.z, vh.w);
    const float4 vi = *(const float4*)(w_ih + rowoff);
    wih[r][0] = pk2(vi.x, vi.y); wih[r][1] = pk2(vi.z, vi.w);
  }
  float fbias = 0.f;
  if (wid == 0 && lane < 32)
    fbias = b_ih[l * HH + gb * ROWS + lane] + b_hh[l * HH + gb * ROWS + lane];

  // row this lane owns after the distributed reduce: bitrev5(lane&31)
  const int rrow = ((lane & 1) << 4) | ((lane & 2) << 2) | (lane & 4) |
                   ((lane & 8) >> 2) | ((lane & 16) >> 4);

  const float* po = outB + scol;            // own slot t (starts at t=0)
  const float* pp = inB + HH + scol;        // prev slot t+1
  float* ps = outB + HH + gb * ROWS + lane; // wave0 store ptr (slot t+1)
  const float* xb = x + (size_t)scol * TT;  // x[scol][t]

  for (int t = 0; t < TT; ++t) {
    // hoisted x gather (layer 0 only) — latency hides under the poll
    float xg0 = 0.f, xg1 = 0.f, xg2 = 0.f, xg3 = 0.f;
    if (l == 0) {
      xg0 = xb[0 * TT + t]; xg1 = xb[1 * TT + t];
      xg2 = xb[2 * TT + t]; xg3 = xb[3 * TT + t];
    }

    // ---- sentinel poll: own h_{t-1} slice (+ prev-layer h_t slice) ----
    u64 o0, o1, p0 = 0, p1 = 0;
    for (;;) {
      o0 = ld_a8(po);
      o1 = ld_a8(po + 2);
      if (l > 0) { p0 = ld_a8(pp); p1 = ld_a8(pp + 2); }
      bool ok = fresh8(o0) & fresh8(o1);
      if (l > 0) ok = ok & fresh8(p0) & fresh8(p1);
      if (__all(ok)) break;
      __builtin_amdgcn_s_sleep(1);
    }
    float hh0 = __uint_as_float((u32)o0), hh1 = __uint_as_float((u32)(o0 >> 32));
    float hh2 = __uint_as_float((u32)o1), hh3 = __uint_as_float((u32)(o1 >> 32));
    float hi0, hi1, hi2, hi3;
    if (l == 0) { hi0 = xg0; hi1 = xg1; hi2 = xg2; hi3 = xg3; }
    else {
      hi0 = __uint_as_float((u32)p0); hi1 = __uint_as_float((u32)(p0 >> 32));
      hi2 = __uint_as_float((u32)p1); hi3 = __uint_as_float((u32)(p1 >> 32));
    }
    const h2 ph0 = pk2(hh0, hh1), ph1 = pk2(hh2, hh3);
    const h2 pi0 = pk2(hi0, hi1), pi1 = pk2(hi2, hi3);

    // ---- per-lane partials: 32 rows x 4 cols, 4 fdot2/row ----
    float acc[ROWS];
#pragma unroll
    for (int r = 0; r < ROWS; ++r)
      acc[r] = dot2(whh[r][1], ph1,
               dot2(whh[r][0], ph0,
               dot2(wih[r][1], pi1,
               dot2(wih[r][0], pi0, 0.f))));

    // ---- distributed reduce: xor-32 pre-level, then 5 halving levels ----
#pragma unroll
    for (int i = 0; i < 32; ++i) acc[i] += __shfl_xor(acc[i], 32, 64);
#pragma unroll
    for (int lv = 0; lv < 5; ++lv) {
      const int m = 1 << lv;
      const int n = 16 >> lv;          // 16,8,4,2,1
      const bool up = (lane & m) != 0;
#pragma unroll
      for (int i = 0; i < 16; ++i) {
        if (i < n) {
          float mine   = up ? acc[i + n] : acc[i];
          float theirs = __shfl_xor(up ? acc[i] : acc[i + n], m, 64);
          acc[i] = mine + theirs;
        }
      }
    }
    if (lane < 32) partial[t & 1][wid][rrow] = acc[0];
    __syncthreads();                    // the ONLY barrier per step

    if (wid == 0 && lane < 32) {
      float s = fbias;
#pragma unroll
      for (int w = 0; w < 8; ++w) s += partial[t & 1][w][lane];
      st_a4(ps, fast_tanh(s));
    }
    po += HH; pp += HH; ps += HH;
    // partial[] race-freedom: a wave's step-(t+2) rewrite of buffer t&1 is
    // gated through other blocks' step-(t+1) publishes, which transitively
    // require OUR wave0's step-t publish, which follows its step-t reads.
  }

  // ---- FC on h3[T-1]: layer-3 group only (weight regs are dead now) ----
  if (l == 3) {
    float wf[ROWS][4];
#pragma unroll
    for (int r = 0; r < ROWS; ++r) {
      const float4 v = *(const float4*)(w_fc + (size_t)(gb * ROWS + r) * HH + scol);
      wf[r][0] = v.x; wf[r][1] = v.y; wf[r][2] = v.z; wf[r][3] = v.w;
    }
    const float* ph = outB + (size_t)TT * HH + scol;
    u64 o0, o1;
    for (;;) {
      o0 = ld_a8(ph);
      o1 = ld_a8(ph + 2);
      if (__all(fresh8(o0) & fresh8(o1))) break;
      __builtin_amdgcn_s_sleep(1);
    }
    float h0 = __uint_as_float((u32)o0), h1 = __uint_as_float((u32)(o0 >> 32));
    float h2v = __uint_as_float((u32)o1), h3 = __uint_as_float((u32)(o1 >> 32));

    float acc[ROWS];
#pragma unroll
    for (int r = 0; r < ROWS; ++r)
      acc[r] = wf[r][0] * h0 + wf[r][1] * h1 + wf[r][2] * h2v + wf[r][3] * h3;
#pragma unroll
    for (int i = 0; i < 32; ++i) acc[i] += __shfl_xor(acc[i], 32, 64);
#pragma unroll
    for (int lv = 0; lv < 5; ++lv) {
      const int m = 1 << lv;
      const int n = 16 >> lv;
      const bool up = (lane & m) != 0;
#pragma unroll
      for (int i = 0; i < 16; ++i) {
        if (i < n) {
          float mine   = up ? acc[i + n] : acc[i];
          float theirs = __shfl_xor(up ? acc[i] : acc[i + n], m, 64);
          acc[i] = mine + theirs;
        }
      }
    }
    if (lane < 32) partial[0][wid][rrow] = acc[0];
    __syncthreads();
    if (wid == 0 && lane < 32) {
      float s = b_fc[gb * ROWS + lane];
#pragma unroll
      for (int w = 0; w < 8; ++w) s += partial[0][w][lane];
      out[gb * ROWS + lane] = s;
    }
  }
}

extern "C" void kernel_launch(void* const* d_in, const int* in_sizes, int n_in,
                              void* d_out, int out_size, void* d_ws, size_t ws_size,
                              hipStream_t stream) {
  const float* x    = (const float*)d_in[0];
  const float* w_ih = (const float*)d_in[1];
  const float* w_hh = (const float*)d_in[2];
  const float* b_ih = (const float*)d_in[3];
  const float* b_hh = (const float*)d_in[4];
  const float* w_fc = (const float*)d_in[5];
  const float* b_fc = (const float*)d_in[6];
  float* out = (float*)d_out;
  float* ws  = (float*)d_ws;

  // 4 exchange buffers (one per layer): (TT+1) x HH floats each.
  // Sentinel-fill, then zero slot 0 (= h_{-1}) of each.
  const size_t bufFloats = (size_t)(TT + 1) * HH;
  hipMemsetAsync(ws, 0xFF, 4 * bufFloats * sizeof(float), stream);
  for (int l = 0; l < 4; ++l)
    hipMemsetAsync(ws + l * bufFloats, 0, HH * sizeof(float), stream);

  rnn_d4<<<NBLK, NTH, 0, stream>>>(x, w_ih, w_hh, b_ih, b_hh,
                                   w_fc, b_fc, out, ws);
}